// Round 6
// baseline (165.763 us; speedup 1.0000x reference)
//
#include <hip/hip_runtime.h>

#define PCNT 128
#define RCdim 256
#define IMG (RCdim*RCdim)
#define PITCH 42        // mod 4 = 2 -> rows alternate bank class (conflict fix, R5)
#define TROWS 36        // 32 + 2*ext2
#define TELEMS (TROWS*PITCH)   // 1512 floats
#define NSLOT 360              // float4 load slots per plane (10 per row)
#define NTHREADS 256

__device__ __forceinline__ float sig_(float x){ return 1.0f/(1.0f+__expf(-x)); }
__device__ __forceinline__ float th_(float x){ float e=__expf(2.0f*x); return 1.0f-2.0f/(e+1.0f); }

// Stage one 36x40 plane tile (pitch 42), origin (R0-2, C0-4), zero-padded OOB.
__device__ __forceinline__ void stage4(const float* __restrict__ src, float* __restrict__ dst,
                                       int R0, int C0, int tid){
#pragma unroll
  for (int j=0;j<2;++j){
    int s = j*NTHREADS + tid;
    if (s < NSLOT){
      int rr = s/10, q = s - rr*10;
      int gr = R0-2+rr, gc = C0-4+4*q;
      float4 v = make_float4(0.f,0.f,0.f,0.f);
      if ((unsigned)gr < 256u && (unsigned)gc < 253u)
        v = *(const float4*)(src + gr*RCdim + gc);
      float* d = dst + rr*PITCH + 4*q;
      *(float2*)(d  ) = make_float2(v.x, v.y);
      *(float2*)(d+2) = make_float2(v.z, v.w);
    }
  }
}

// 8-col window via 4x ds_read_b64 (col0 even), rows row0..row0+2
__device__ __forceinline__ void load8(const float* __restrict__ T, int row0, int col0, float v[3][8]){
#pragma unroll
  for (int dy=0;dy<3;++dy){
    const float2* p = (const float2*)&T[(row0+dy)*PITCH + col0];
    float2 a=p[0],b=p[1],c=p[2],d=p[3];
    v[dy][0]=a.x; v[dy][1]=a.y; v[dy][2]=b.x; v[dy][3]=b.y;
    v[dy][4]=c.x; v[dy][5]=c.y; v[dy][6]=d.x; v[dy][7]=d.y;
  }
}

// 3x3 cross-correlation, 1x4 strip; pixel k center col = window_base + OFF+1+k
template<int OFF>
__device__ __forceinline__ void conv_acc(const float v[3][8], const float w9[9], float o[4]){
#pragma unroll
  for (int ky=0; ky<3; ++ky)
#pragma unroll
    for (int kx=0; kx<3; ++kx){
      const float w = w9[ky*3+kx];
#pragma unroll
      for (int k=0;k<4;++k) o[k] = fmaf(w, v[ky][k+kx+OFF], o[k]);
    }
}

__device__ __forceinline__ void load_w18(const float* __restrict__ g, float w0[9], float w1[9]){
#pragma unroll
  for (int i=0;i<9;++i){ w0[i]=g[i]; w1[i]=g[9+i]; }
}
__device__ __forceinline__ void load_w9(const float* __restrict__ g, float w0[9]){
#pragma unroll
  for (int i=0;i<9;++i) w0[i]=g[i];
}

__global__ void init_out(const float* __restrict__ bias, float* __restrict__ out){
  int i = blockIdx.x * NTHREADS + threadIdx.x;
  out[i] = bias[i];
}

// out[px] = bias[px] + sum_p ns[p][px] * w_read[px][p]
__global__ void __launch_bounds__(NTHREADS)
reduce_out(const float* __restrict__ ns, const float* __restrict__ w_read,
           const float* __restrict__ bias, float* __restrict__ out){
  const int px = blockIdx.x * NTHREADS + threadIdx.x;
  float acc = bias[px];
  const float* wr = w_read + (size_t)px * PCNT;
#pragma unroll 4
  for (int p0 = 0; p0 < PCNT; p0 += 4){
    const float4 w4 = *(const float4*)&wr[p0];
    acc = fmaf(ns[(size_t)(p0  )*IMG + px], w4.x,
          fmaf(ns[(size_t)(p0+1)*IMG + px], w4.y,
          fmaf(ns[(size_t)(p0+2)*IMG + px], w4.z,
          fmaf(ns[(size_t)(p0+3)*IMG + px], w4.w, acc))));
  }
  out[px] = acc;
}

// 4 LDS planes: B0,B1 = conv sources (restaged per half); B2 = h_a -> hr_a (in place);
// B3 = h_{a+1} -> hr_{a+1} (in place).
// hr region: rows 1..34, cols 3..36. Interior (rows 2..33, cols 4..35) is each
// thread's own output strip -> reset conv fuses with the strip convs (same windows).
// Ring (132 px) handled by 82 extra tasks on tid<82.
template<bool SPLIT>
__global__ void __launch_bounds__(NTHREADS, 6)
gru_fused(const float* __restrict__ x, const float* __restrict__ h,
          const float* __restrict__ w_reset, const float* __restrict__ b_reset,
          const float* __restrict__ w_update, const float* __restrict__ b_update,
          const float* __restrict__ w_out, const float* __restrict__ b_out,
          const float* __restrict__ w_read, float* __restrict__ ws,
          float* __restrict__ out)
{
  __shared__ float sm[4][TELEMS];  // 24192 B -> 6 blocks/CU
  const int tid  = threadIdx.x;
  const int bid  = blockIdx.x;
  const int pg   = bid & 15;
  const int tile = bid >> 4;
  const int R0 = (tile >> 3) * 32;
  const int C0 = (tile & 7) * 32;
  const int trow = tid >> 3;
  const int tcol = (tid & 7) * 4;
  const int gidx = (R0 + trow) * RCdim + C0 + tcol;

  // ring task geometry (hr halo): window base col rwb (even), rows rrow-1..rrow+1,
  // conv_acc<0> centers = rwb+1+k; write k in [rk0, rk0+rkn)
  const bool ringAct = tid < 82;
  int rrow=1, rwb=2, rk0=0, rkn=0;
  if (tid < 9)       { rrow = 1;            rwb = 2+4*tid;      rk0 = 0; rkn = (tid==8)?2:4; }
  else if (tid < 18) { int u=tid-9; rrow=34; rwb = 2+4*u;       rk0 = 0; rkn = (u==8)?2:4; }
  else if (tid < 50) { rrow = 2+(tid-18);   rwb = 2;            rk0 = 0; rkn = 1; }
  else if (tid < 82) { rrow = 2+(tid-50);   rwb = 32;           rk0 = 3; rkn = 1; }

  float acc[4] = {0.f,0.f,0.f,0.f};

#pragma unroll 1
  for (int it = 0; it < 4; ++it){
    const bool low = (it < 2);
    const int t = it & 1;
    int a, ph;
    const float *s0, *s1;
    if (low){
      a = 4*pg + 2*t; ph = 64 + 2*pg + t;
      s0 = x + (size_t)(2*a  )*IMG;   // x_{2a}, x_{2a+1}
      s1 = x + (size_t)(2*a+2)*IMG;   // x_{2a+2}, x_{2a+3}
    } else {
      a = 64 + 4*pg + 2*t; ph = 96 + 2*pg + t;
      const int base = 8*pg + 4*t;
      s0 = h + (size_t)base*IMG;      // h_{base}, h_{base+1}
      s1 = h + (size_t)(base+2)*IMG;  // h_{base+2}, h_{base+3}
    }

    __syncthreads();   // protect B0..B3 from previous iteration's readers
    stage4(s0,                     sm[0], R0,C0,tid);
    stage4(s0 + IMG,               sm[1], R0,C0,tid);
    stage4(h + (size_t)a*IMG,      sm[2], R0,C0,tid);
    __syncthreads();

    // ================= half 1: plane pair for reset_a, plant a (if low), update part1 =================
    float wr0[9], wr1[9];
    load_w18(w_reset + a*18, wr0, wr1);
    const float br0 = b_reset[a];

    float W0[3][8], W1[3][8];
    load8(sm[0], trow+1, tcol+2, W0);
    load8(sm[1], trow+1, tcol+2, W1);
    float ra[4] = {br0,br0,br0,br0};
    conv_acc<1>(W0, wr0, ra); conv_acc<1>(W1, wr1, ra);

    float upd[4], hc[4];
    {
      float wh0[9];
      load_w9(w_update + ph*18, wh0);
      const float buh = b_update[ph];
      float WH[3][8];
      load8(sm[2], trow+1, tcol+2, WH);
      upd[0]=buh; upd[1]=buh; upd[2]=buh; upd[3]=buh;
      conv_acc<1>(WH, wh0, upd);
#pragma unroll
      for (int k=0;k<4;++k) hc[k] = WH[1][k+2];
    }

    if (low){
      float wua[9],wub[9],woa[9],wob[9];
      load_w18(w_update + a*18, wua, wub);
      load_w18(w_out    + a*18, woa, wob);
      const float bu=b_update[a], bo=b_out[a];
      float uo[4]={bu,bu,bu,bu}, co[4]={bo,bo,bo,bo};
      conv_acc<1>(W0, wua, uo); conv_acc<1>(W1, wub, uo);
      conv_acc<1>(W0, woa, co); conv_acc<1>(W1, wob, co);
      float ns0[4];
#pragma unroll
      for (int k=0;k<4;++k){ float u=sig_(uo[k]); ns0[k]=hc[k]+u*(th_(co[k])-hc[k]); }
      if (SPLIT){
        *(float4*)&ws[(size_t)a*IMG + gidx] = make_float4(ns0[0],ns0[1],ns0[2],ns0[3]);
      } else {
#pragma unroll
        for (int k=0;k<4;++k)
          acc[k] = fmaf(ns0[k], w_read[(size_t)(gidx+k)*PCNT + a], acc[k]);
      }
    }

    float rsig[4];
    if (ringAct){
      float rv0[3][8], rv1[3][8];
      load8(sm[0], rrow-1, rwb, rv0);
      load8(sm[1], rrow-1, rwb, rv1);
      float rr[4] = {br0,br0,br0,br0};
      conv_acc<0>(rv0, wr0, rr); conv_acc<0>(rv1, wr1, rr);
#pragma unroll
      for (int k=0;k<4;++k) rsig[k] = sig_(rr[k]);
    }
    __syncthreads();   // all reads of B0,B1,B2 done

    // ================= half 2 stage + hr_a in-place write =================
    stage4(s1,                      sm[0], R0,C0,tid);
    stage4(s1 + IMG,                sm[1], R0,C0,tid);
    stage4(h + (size_t)(a+1)*IMG,   sm[3], R0,C0,tid);
    { // interior hr_a = h_center * sig(ra)
      float* d = &sm[2][(trow+2)*PITCH + tcol+4];
      *(float2*)(d  ) = make_float2(hc[0]*sig_(ra[0]), hc[1]*sig_(ra[1]));
      *(float2*)(d+2) = make_float2(hc[2]*sig_(ra[2]), hc[3]*sig_(ra[3]));
    }
    if (ringAct){
      for (int k=rk0; k<rk0+rkn; ++k){
        int o = rrow*PITCH + rwb+1+k;
        sm[2][o] = sm[2][o] * rsig[k];
      }
    }
    __syncthreads();

    // ================= half 2 compute: reset_{a+1}, plant a+1 (if low), update part2 =================
    load_w18(w_reset + (a+1)*18, wr0, wr1);
    const float br1 = b_reset[a+1];
    load8(sm[0], trow+1, tcol+2, W0);
    load8(sm[1], trow+1, tcol+2, W1);
    float ra2[4] = {br1,br1,br1,br1};
    conv_acc<1>(W0, wr0, ra2); conv_acc<1>(W1, wr1, ra2);

    float hc2[4];
    {
      float wh1[9];
      load_w9(w_update + ph*18 + 9, wh1);
      float WH[3][8];
      load8(sm[3], trow+1, tcol+2, WH);
      conv_acc<1>(WH, wh1, upd);
#pragma unroll
      for (int k=0;k<4;++k) hc2[k] = WH[1][k+2];
    }

    if (low){
      float wua[9],wub[9],woa[9],wob[9];
      load_w18(w_update + (a+1)*18, wua, wub);
      load_w18(w_out    + (a+1)*18, woa, wob);
      const float bu=b_update[a+1], bo=b_out[a+1];
      float uo[4]={bu,bu,bu,bu}, co[4]={bo,bo,bo,bo};
      conv_acc<1>(W0, wua, uo); conv_acc<1>(W1, wub, uo);
      conv_acc<1>(W0, woa, co); conv_acc<1>(W1, wob, co);
      float ns1[4];
#pragma unroll
      for (int k=0;k<4;++k){ float u=sig_(uo[k]); ns1[k]=hc2[k]+u*(th_(co[k])-hc2[k]); }
      if (SPLIT){
        *(float4*)&ws[(size_t)(a+1)*IMG + gidx] = make_float4(ns1[0],ns1[1],ns1[2],ns1[3]);
      } else {
#pragma unroll
        for (int k=0;k<4;++k)
          acc[k] = fmaf(ns1[k], w_read[(size_t)(gidx+k)*PCNT + (a+1)], acc[k]);
      }
    }

    float rsig2[4];
    if (ringAct){
      float rv0[3][8], rv1[3][8];
      load8(sm[0], rrow-1, rwb, rv0);
      load8(sm[1], rrow-1, rwb, rv1);
      float rr[4] = {br1,br1,br1,br1};
      conv_acc<0>(rv0, wr0, rr); conv_acc<0>(rv1, wr1, rr);
#pragma unroll
      for (int k=0;k<4;++k) rsig2[k] = sig_(rr[k]);
    }
    __syncthreads();   // all reads of B3 (update part2) done

    // ================= hr_{a+1} in-place write =================
    {
      float* d = &sm[3][(trow+2)*PITCH + tcol+4];
      *(float2*)(d  ) = make_float2(hc2[0]*sig_(ra2[0]), hc2[1]*sig_(ra2[1]));
      *(float2*)(d+2) = make_float2(hc2[2]*sig_(ra2[2]), hc2[3]*sig_(ra2[3]));
    }
    if (ringAct){
      for (int k=rk0; k<rk0+rkn; ++k){
        int o = rrow*PITCH + rwb+1+k;
        sm[3][o] = sm[3][o] * rsig2[k];
      }
    }
    __syncthreads();

    // ================= cand conv over (hr_a, hr_{a+1}) + blend for high plant =================
    {
      float woh0[9], woh1[9];
      load_w18(w_out + ph*18, woh0, woh1);
      const float bo = b_out[ph];
      float co[4]={bo,bo,bo,bo};
      load8(sm[2], trow+1, tcol+2, W0);
      load8(sm[3], trow+1, tcol+2, W1);
      conv_acc<1>(W0, woh0, co); conv_acc<1>(W1, woh1, co);
      const float4 hp4 = *(const float4*)&h[(size_t)ph*IMG + gidx];
      const float hp[4] = {hp4.x,hp4.y,hp4.z,hp4.w};
      float nsH[4];
#pragma unroll
      for (int k=0;k<4;++k){
        float u = sig_(upd[k]);
        nsH[k] = hp[k] + u*(th_(co[k])-hp[k]);
      }
      if (SPLIT){
        *(float4*)&ws[(size_t)ph*IMG + gidx] = make_float4(nsH[0],nsH[1],nsH[2],nsH[3]);
      } else {
#pragma unroll
        for (int k=0;k<4;++k)
          acc[k] = fmaf(nsH[k], w_read[(size_t)(gidx+k)*PCNT + ph], acc[k]);
      }
    }
  }

  if (!SPLIT){
#pragma unroll
    for (int k=0;k<4;++k) atomicAdd(&out[gidx+k], acc[k]);
  }
}

extern "C" void kernel_launch(void* const* d_in, const int* in_sizes, int n_in,
                              void* d_out, int out_size, void* d_ws, size_t ws_size,
                              hipStream_t stream) {
  const float* x     = (const float*)d_in[0];
  const float* h     = (const float*)d_in[1];
  const float* wrst  = (const float*)d_in[2];
  const float* brst  = (const float*)d_in[3];
  const float* wupd  = (const float*)d_in[4];
  const float* bupd  = (const float*)d_in[5];
  const float* wout  = (const float*)d_in[6];
  const float* bout  = (const float*)d_in[7];
  const float* wread = (const float*)d_in[8];
  const float* bias  = (const float*)d_in[9];
  float* out = (float*)d_out;
  float* ws  = (float*)d_ws;

  const bool split = ws_size >= (size_t)PCNT * IMG * sizeof(float);
  if (split){
    hipLaunchKernelGGL(gru_fused<true>, dim3(64*16), dim3(NTHREADS), 0, stream,
                       x, h, wrst, brst, wupd, bupd, wout, bout, wread, ws, out);
    hipLaunchKernelGGL(reduce_out, dim3(IMG/NTHREADS), dim3(NTHREADS), 0, stream,
                       ws, wread, bias, out);
  } else {
    hipLaunchKernelGGL(init_out, dim3(IMG/NTHREADS), dim3(NTHREADS), 0, stream, bias, out);
    hipLaunchKernelGGL(gru_fused<false>, dim3(64*16), dim3(NTHREADS), 0, stream,
                       x, h, wrst, brst, wupd, bupd, wout, bout, wread, ws, out);
  }
}

// Round 7
// 165.556 us; speedup vs baseline: 1.0012x; 1.0012x over previous
//
#include <hip/hip_runtime.h>

#define PCNT 128
#define RCdim 256
#define IMG (RCdim*RCdim)
#define PITCH 42        // mod 4 = 2 -> rows alternate bank class (conflict fix, R5)
#define TROWS 36        // 32 + 2*ext2
#define TELEMS (TROWS*PITCH)   // 1512 floats
#define NSLOT 360              // float4 load slots per plane (10 per row)
#define NTHREADS 256

__device__ __forceinline__ float sig_(float x){ return 1.0f/(1.0f+__expf(-x)); }
__device__ __forceinline__ float th_(float x){ float e=__expf(2.0f*x); return 1.0f-2.0f/(e+1.0f); }

// Stage one 36x40 plane tile (pitch 42), origin (R0-2, C0-4), zero-padded OOB.
__device__ __forceinline__ void stage4(const float* __restrict__ src, float* __restrict__ dst,
                                       int R0, int C0, int tid){
#pragma unroll
  for (int j=0;j<2;++j){
    int s = j*NTHREADS + tid;
    if (s < NSLOT){
      int rr = s/10, q = s - rr*10;
      int gr = R0-2+rr, gc = C0-4+4*q;
      float4 v = make_float4(0.f,0.f,0.f,0.f);
      if ((unsigned)gr < 256u && (unsigned)gc < 253u)
        v = *(const float4*)(src + gr*RCdim + gc);
      float* d = dst + rr*PITCH + 4*q;
      *(float2*)(d  ) = make_float2(v.x, v.y);
      *(float2*)(d+2) = make_float2(v.z, v.w);
    }
  }
}

// 8-col window via 4x ds_read_b64 (col0 even), rows row0..row0+2
__device__ __forceinline__ void load8(const float* __restrict__ T, int row0, int col0, float v[3][8]){
#pragma unroll
  for (int dy=0;dy<3;++dy){
    const float2* p = (const float2*)&T[(row0+dy)*PITCH + col0];
    float2 a=p[0],b=p[1],c=p[2],d=p[3];
    v[dy][0]=a.x; v[dy][1]=a.y; v[dy][2]=b.x; v[dy][3]=b.y;
    v[dy][4]=c.x; v[dy][5]=c.y; v[dy][6]=d.x; v[dy][7]=d.y;
  }
}

// 3x3 cross-correlation, 1x4 strip; pixel k center col = window_base + OFF+1+k
template<int OFF>
__device__ __forceinline__ void conv_acc(const float v[3][8], const float w9[9], float o[4]){
#pragma unroll
  for (int ky=0; ky<3; ++ky)
#pragma unroll
    for (int kx=0; kx<3; ++kx){
      const float w = w9[ky*3+kx];
#pragma unroll
      for (int k=0;k<4;++k) o[k] = fmaf(w, v[ky][k+kx+OFF], o[k]);
    }
}

__device__ __forceinline__ void load_w18(const float* __restrict__ g, float w0[9], float w1[9]){
#pragma unroll
  for (int i=0;i<9;++i){ w0[i]=g[i]; w1[i]=g[9+i]; }
}
__device__ __forceinline__ void load_w9(const float* __restrict__ g, float w0[9]){
#pragma unroll
  for (int i=0;i<9;++i) w0[i]=g[i];
}

__global__ void init_out(const float* __restrict__ bias, float* __restrict__ out){
  int i = blockIdx.x * NTHREADS + threadIdx.x;
  out[i] = bias[i];
}

// out[px] = bias[px] + sum_p ns[p][px] * w_read[px][p]
__global__ void __launch_bounds__(NTHREADS)
reduce_out(const float* __restrict__ ns, const float* __restrict__ w_read,
           const float* __restrict__ bias, float* __restrict__ out){
  const int px = blockIdx.x * NTHREADS + threadIdx.x;
  float acc = bias[px];
  const float* wr = w_read + (size_t)px * PCNT;
#pragma unroll 4
  for (int p0 = 0; p0 < PCNT; p0 += 4){
    const float4 w4 = *(const float4*)&wr[p0];
    acc = fmaf(ns[(size_t)(p0  )*IMG + px], w4.x,
          fmaf(ns[(size_t)(p0+1)*IMG + px], w4.y,
          fmaf(ns[(size_t)(p0+2)*IMG + px], w4.z,
          fmaf(ns[(size_t)(p0+3)*IMG + px], w4.w, acc))));
  }
  out[px] = acc;
}

// 4 LDS planes: B0,B1 = conv sources (restaged per half); B2 = h_a -> hr_a (in place);
// B3 = h_{a+1} -> hr_{a+1} (in place). Reset conv fused into per-thread strip convs
// (interior); 1-px halo ring via 82 side tasks. Liveness-ordered for VGPR<=96 (R7):
// strip convs (W0/W1 die) BEFORE update conv (WH born); weight arrays reused.
template<bool SPLIT>
__global__ void __launch_bounds__(NTHREADS, 5)
gru_fused(const float* __restrict__ x, const float* __restrict__ h,
          const float* __restrict__ w_reset, const float* __restrict__ b_reset,
          const float* __restrict__ w_update, const float* __restrict__ b_update,
          const float* __restrict__ w_out, const float* __restrict__ b_out,
          const float* __restrict__ w_read, float* __restrict__ ws,
          float* __restrict__ out)
{
  __shared__ float sm[4][TELEMS];  // 24192 B
  const int tid  = threadIdx.x;
  const int bid  = blockIdx.x;
  const int pg   = bid & 15;
  const int tile = bid >> 4;
  const int R0 = (tile >> 3) * 32;
  const int C0 = (tile & 7) * 32;
  const int trow = tid >> 3;
  const int tcol = (tid & 7) * 4;
  const int gidx = (R0 + trow) * RCdim + C0 + tcol;

  // ring task geometry (hr halo): window base col rwb (even), rows rrow-1..rrow+1,
  // conv_acc<0> centers = rwb+1+k; write k in [rk0, rk0+rkn)
  const bool ringAct = tid < 82;
  int rrow=1, rwb=2, rk0=0, rkn=0;
  if (tid < 9)       { rrow = 1;            rwb = 2+4*tid;      rk0 = 0; rkn = (tid==8)?2:4; }
  else if (tid < 18) { int u=tid-9; rrow=34; rwb = 2+4*u;       rk0 = 0; rkn = (u==8)?2:4; }
  else if (tid < 50) { rrow = 2+(tid-18);   rwb = 2;            rk0 = 0; rkn = 1; }
  else if (tid < 82) { rrow = 2+(tid-50);   rwb = 32;           rk0 = 3; rkn = 1; }

  float acc[4] = {0.f,0.f,0.f,0.f};

#pragma unroll 1
  for (int it = 0; it < 4; ++it){
    const bool low = (it < 2);
    const int t = it & 1;
    int a, ph;
    const float *s0, *s1;
    if (low){
      a = 4*pg + 2*t; ph = 64 + 2*pg + t;
      s0 = x + (size_t)(2*a  )*IMG;
      s1 = x + (size_t)(2*a+2)*IMG;
    } else {
      a = 64 + 4*pg + 2*t; ph = 96 + 2*pg + t;
      const int base = 8*pg + 4*t;
      s0 = h + (size_t)base*IMG;
      s1 = h + (size_t)(base+2)*IMG;
    }

    __syncthreads();   // protect B0..B3 from previous iteration's readers
    stage4(s0,                     sm[0], R0,C0,tid);
    stage4(s0 + IMG,               sm[1], R0,C0,tid);
    stage4(h + (size_t)a*IMG,      sm[2], R0,C0,tid);
    __syncthreads();

    // ===== half 1: strip convs over (B0,B1), then update part1 over B2 =====
    float ra[4], uo[4], co[4];
    {
      float W0[3][8], W1[3][8];
      load8(sm[0], trow+1, tcol+2, W0);
      load8(sm[1], trow+1, tcol+2, W1);
      float wt0[9], wt1[9];
      load_w18(w_reset + a*18, wt0, wt1);
      const float br0 = b_reset[a];
      ra[0]=br0; ra[1]=br0; ra[2]=br0; ra[3]=br0;
      conv_acc<1>(W0, wt0, ra); conv_acc<1>(W1, wt1, ra);
      if (low){
        load_w18(w_update + a*18, wt0, wt1);
        const float bu = b_update[a];
        uo[0]=bu; uo[1]=bu; uo[2]=bu; uo[3]=bu;
        conv_acc<1>(W0, wt0, uo); conv_acc<1>(W1, wt1, uo);
        load_w18(w_out + a*18, wt0, wt1);
        const float bo = b_out[a];
        co[0]=bo; co[1]=bo; co[2]=bo; co[3]=bo;
        conv_acc<1>(W0, wt0, co); conv_acc<1>(W1, wt1, co);
      }
    } // W0/W1 dead

    float upd[4], hc[4];
    {
      float wh0[9];
      load_w9(w_update + ph*18, wh0);
      const float buh = b_update[ph];
      float WH[3][8];
      load8(sm[2], trow+1, tcol+2, WH);
      upd[0]=buh; upd[1]=buh; upd[2]=buh; upd[3]=buh;
      conv_acc<1>(WH, wh0, upd);
#pragma unroll
      for (int k=0;k<4;++k) hc[k] = WH[1][k+2];
    }

    if (low){
      float ns0[4];
#pragma unroll
      for (int k=0;k<4;++k){ float u=sig_(uo[k]); ns0[k]=hc[k]+u*(th_(co[k])-hc[k]); }
      if (SPLIT){
        *(float4*)&ws[(size_t)a*IMG + gidx] = make_float4(ns0[0],ns0[1],ns0[2],ns0[3]);
      } else {
#pragma unroll
        for (int k=0;k<4;++k)
          acc[k] = fmaf(ns0[k], w_read[(size_t)(gidx+k)*PCNT + a], acc[k]);
      }
    }

    float rsig[4];
    if (ringAct){
      float rv0[3][8], rv1[3][8];
      load8(sm[0], rrow-1, rwb, rv0);
      load8(sm[1], rrow-1, rwb, rv1);
      float wt0[9], wt1[9];
      load_w18(w_reset + a*18, wt0, wt1);
      const float br0 = b_reset[a];
      float rr[4] = {br0,br0,br0,br0};
      conv_acc<0>(rv0, wt0, rr); conv_acc<0>(rv1, wt1, rr);
#pragma unroll
      for (int k=0;k<4;++k) rsig[k] = sig_(rr[k]);
    }
    __syncthreads();   // all reads of B0,B1,B2 done

    // ===== half 2 stage + hr_a in-place write =====
    stage4(s1,                      sm[0], R0,C0,tid);
    stage4(s1 + IMG,                sm[1], R0,C0,tid);
    stage4(h + (size_t)(a+1)*IMG,   sm[3], R0,C0,tid);
    { // interior hr_a = h_center * sig(ra)
      float* d = &sm[2][(trow+2)*PITCH + tcol+4];
      *(float2*)(d  ) = make_float2(hc[0]*sig_(ra[0]), hc[1]*sig_(ra[1]));
      *(float2*)(d+2) = make_float2(hc[2]*sig_(ra[2]), hc[3]*sig_(ra[3]));
    }
    if (ringAct){
      for (int k=rk0; k<rk0+rkn; ++k){
        int o = rrow*PITCH + rwb+1+k;
        sm[2][o] = sm[2][o] * rsig[k];
      }
    }
    __syncthreads();

    // ===== half 2: strip convs over restaged (B0,B1), update part2 over B3 =====
    float hc2[4];
    {
      float W0[3][8], W1[3][8];
      load8(sm[0], trow+1, tcol+2, W0);
      load8(sm[1], trow+1, tcol+2, W1);
      float wt0[9], wt1[9];
      load_w18(w_reset + (a+1)*18, wt0, wt1);
      const float br1 = b_reset[a+1];
      ra[0]=br1; ra[1]=br1; ra[2]=br1; ra[3]=br1;
      conv_acc<1>(W0, wt0, ra); conv_acc<1>(W1, wt1, ra);
      if (low){
        load_w18(w_update + (a+1)*18, wt0, wt1);
        const float bu = b_update[a+1];
        uo[0]=bu; uo[1]=bu; uo[2]=bu; uo[3]=bu;
        conv_acc<1>(W0, wt0, uo); conv_acc<1>(W1, wt1, uo);
        load_w18(w_out + (a+1)*18, wt0, wt1);
        const float bo = b_out[a+1];
        co[0]=bo; co[1]=bo; co[2]=bo; co[3]=bo;
        conv_acc<1>(W0, wt0, co); conv_acc<1>(W1, wt1, co);
      }
    }
    {
      float wh1[9];
      load_w9(w_update + ph*18 + 9, wh1);
      float WH[3][8];
      load8(sm[3], trow+1, tcol+2, WH);
      conv_acc<1>(WH, wh1, upd);
#pragma unroll
      for (int k=0;k<4;++k) hc2[k] = WH[1][k+2];
    }

    if (low){
      float ns1[4];
#pragma unroll
      for (int k=0;k<4;++k){ float u=sig_(uo[k]); ns1[k]=hc2[k]+u*(th_(co[k])-hc2[k]); }
      if (SPLIT){
        *(float4*)&ws[(size_t)(a+1)*IMG + gidx] = make_float4(ns1[0],ns1[1],ns1[2],ns1[3]);
      } else {
#pragma unroll
        for (int k=0;k<4;++k)
          acc[k] = fmaf(ns1[k], w_read[(size_t)(gidx+k)*PCNT + (a+1)], acc[k]);
      }
    }

    float rsig2[4];
    if (ringAct){
      float rv0[3][8], rv1[3][8];
      load8(sm[0], rrow-1, rwb, rv0);
      load8(sm[1], rrow-1, rwb, rv1);
      float wt0[9], wt1[9];
      load_w18(w_reset + (a+1)*18, wt0, wt1);
      const float br1 = b_reset[a+1];
      float rr[4] = {br1,br1,br1,br1};
      conv_acc<0>(rv0, wt0, rr); conv_acc<0>(rv1, wt1, rr);
#pragma unroll
      for (int k=0;k<4;++k) rsig2[k] = sig_(rr[k]);
    }
    __syncthreads();   // all reads of B3 (update part2) done

    // ===== hr_{a+1} in-place write =====
    {
      float* d = &sm[3][(trow+2)*PITCH + tcol+4];
      *(float2*)(d  ) = make_float2(hc2[0]*sig_(ra[0]), hc2[1]*sig_(ra[1]));
      *(float2*)(d+2) = make_float2(hc2[2]*sig_(ra[2]), hc2[3]*sig_(ra[3]));
    }
    if (ringAct){
      for (int k=rk0; k<rk0+rkn; ++k){
        int o = rrow*PITCH + rwb+1+k;
        sm[3][o] = sm[3][o] * rsig2[k];
      }
    }
    __syncthreads();

    // ===== cand conv over (hr_a, hr_{a+1}) + blend for high plant =====
    {
      float W0[3][8], W1[3][8];
      load8(sm[2], trow+1, tcol+2, W0);
      load8(sm[3], trow+1, tcol+2, W1);
      float wt0[9], wt1[9];
      load_w18(w_out + ph*18, wt0, wt1);
      const float bo = b_out[ph];
      float cc[4]={bo,bo,bo,bo};
      conv_acc<1>(W0, wt0, cc); conv_acc<1>(W1, wt1, cc);
      const float4 hp4 = *(const float4*)&h[(size_t)ph*IMG + gidx];
      const float hp[4] = {hp4.x,hp4.y,hp4.z,hp4.w};
      float nsH[4];
#pragma unroll
      for (int k=0;k<4;++k){
        float u = sig_(upd[k]);
        nsH[k] = hp[k] + u*(th_(cc[k])-hp[k]);
      }
      if (SPLIT){
        *(float4*)&ws[(size_t)ph*IMG + gidx] = make_float4(nsH[0],nsH[1],nsH[2],nsH[3]);
      } else {
#pragma unroll
        for (int k=0;k<4;++k)
          acc[k] = fmaf(nsH[k], w_read[(size_t)(gidx+k)*PCNT + ph], acc[k]);
      }
    }
  }

  if (!SPLIT){
#pragma unroll
    for (int k=0;k<4;++k) atomicAdd(&out[gidx+k], acc[k]);
  }
}

extern "C" void kernel_launch(void* const* d_in, const int* in_sizes, int n_in,
                              void* d_out, int out_size, void* d_ws, size_t ws_size,
                              hipStream_t stream) {
  const float* x     = (const float*)d_in[0];
  const float* h     = (const float*)d_in[1];
  const float* wrst  = (const float*)d_in[2];
  const float* brst  = (const float*)d_in[3];
  const float* wupd  = (const float*)d_in[4];
  const float* bupd  = (const float*)d_in[5];
  const float* wout  = (const float*)d_in[6];
  const float* bout  = (const float*)d_in[7];
  const float* wread = (const float*)d_in[8];
  const float* bias  = (const float*)d_in[9];
  float* out = (float*)d_out;
  float* ws  = (float*)d_ws;

  const bool split = ws_size >= (size_t)PCNT * IMG * sizeof(float);
  if (split){
    hipLaunchKernelGGL(gru_fused<true>, dim3(64*16), dim3(NTHREADS), 0, stream,
                       x, h, wrst, brst, wupd, bupd, wout, bout, wread, ws, out);
    hipLaunchKernelGGL(reduce_out, dim3(IMG/NTHREADS), dim3(NTHREADS), 0, stream,
                       ws, wread, bias, out);
  } else {
    hipLaunchKernelGGL(init_out, dim3(IMG/NTHREADS), dim3(NTHREADS), 0, stream, bias, out);
    hipLaunchKernelGGL(gru_fused<false>, dim3(64*16), dim3(NTHREADS), 0, stream,
                       x, h, wrst, brst, wupd, bupd, wout, bout, wread, ws, out);
  }
}

// Round 8
// 94.422 us; speedup vs baseline: 1.7556x; 1.7534x over previous
//
#include <hip/hip_runtime.h>

#define PCNT 128
#define RCdim 256
#define IMG (RCdim*RCdim)
#define PITCH 42        // mod 4 = 2 -> rows alternate bank class (conflict fix, R5)
#define TROWS 36        // 32 + 2*ext2
#define TELEMS (TROWS*PITCH)   // 1512 floats
#define NSLOT 360              // float4 load slots per plane (10 per row)
#define NTHREADS 256

__device__ __forceinline__ float sig_(float x){ return 1.0f/(1.0f+__expf(-x)); }
__device__ __forceinline__ float th_(float x){ float e=__expf(2.0f*x); return 1.0f-2.0f/(e+1.0f); }

// Stage one 36x40 plane tile (pitch 42), origin (R0-2, C0-4), zero-padded OOB.
__device__ __forceinline__ void stage4(const float* __restrict__ src, float* __restrict__ dst,
                                       int R0, int C0, int tid){
#pragma unroll
  for (int j=0;j<2;++j){
    int s = j*NTHREADS + tid;
    if (s < NSLOT){
      int rr = s/10, q = s - rr*10;
      int gr = R0-2+rr, gc = C0-4+4*q;
      float4 v = make_float4(0.f,0.f,0.f,0.f);
      if ((unsigned)gr < 256u && (unsigned)gc < 253u)
        v = *(const float4*)(src + gr*RCdim + gc);
      float* d = dst + rr*PITCH + 4*q;
      *(float2*)(d  ) = make_float2(v.x, v.y);
      *(float2*)(d+2) = make_float2(v.z, v.w);
    }
  }
}

// 8-col window via 4x ds_read_b64 (col0 even), rows row0..row0+2
__device__ __forceinline__ void load8(const float* __restrict__ T, int row0, int col0, float v[3][8]){
#pragma unroll
  for (int dy=0;dy<3;++dy){
    const float2* p = (const float2*)&T[(row0+dy)*PITCH + col0];
    float2 a=p[0],b=p[1],c=p[2],d=p[3];
    v[dy][0]=a.x; v[dy][1]=a.y; v[dy][2]=b.x; v[dy][3]=b.y;
    v[dy][4]=c.x; v[dy][5]=c.y; v[dy][6]=d.x; v[dy][7]=d.y;
  }
}

// 3x3 cross-correlation, 1x4 strip; pixel k center col = window_base + OFF+1+k
template<int OFF>
__device__ __forceinline__ void conv_acc(const float v[3][8], const float w9[9], float o[4]){
#pragma unroll
  for (int ky=0; ky<3; ++ky)
#pragma unroll
    for (int kx=0; kx<3; ++kx){
      const float w = w9[ky*3+kx];
#pragma unroll
      for (int k=0;k<4;++k) o[k] = fmaf(w, v[ky][k+kx+OFF], o[k]);
    }
}

__device__ __forceinline__ void load_w18(const float* __restrict__ g, float w0[9], float w1[9]){
#pragma unroll
  for (int i=0;i<9;++i){ w0[i]=g[i]; w1[i]=g[9+i]; }
}
__device__ __forceinline__ void load_w9(const float* __restrict__ g, float w0[9]){
#pragma unroll
  for (int i=0;i<9;++i) w0[i]=g[i];
}

__global__ void init_out(const float* __restrict__ bias, float* __restrict__ out){
  int i = blockIdx.x * NTHREADS + threadIdx.x;
  out[i] = bias[i];
}

// out[px] = bias[px] + sum_p ns[p][px] * w_read[px][p]
__global__ void __launch_bounds__(NTHREADS)
reduce_out(const float* __restrict__ ns, const float* __restrict__ w_read,
           const float* __restrict__ bias, float* __restrict__ out){
  const int px = blockIdx.x * NTHREADS + threadIdx.x;
  float acc = bias[px];
  const float* wr = w_read + (size_t)px * PCNT;
#pragma unroll 4
  for (int p0 = 0; p0 < PCNT; p0 += 4){
    const float4 w4 = *(const float4*)&wr[p0];
    acc = fmaf(ns[(size_t)(p0  )*IMG + px], w4.x,
          fmaf(ns[(size_t)(p0+1)*IMG + px], w4.y,
          fmaf(ns[(size_t)(p0+2)*IMG + px], w4.z,
          fmaf(ns[(size_t)(p0+3)*IMG + px], w4.w, acc))));
  }
  out[px] = acc;
}

// 4 LDS planes: B0,B1 = conv sources (restaged per half); B2 = h_a -> hr_a (in place);
// B3 = h_{a+1} -> hr_{a+1} (in place). Reset conv fused into per-thread strip convs
// (interior); 1-px halo ring via 82 side tasks (statically-indexed writes, no scratch).
// launch_bounds(256,4): 128 VGPR budget — the no-spill regime (R6/R7 caps of 80/96 spilled ~500MB).
template<bool SPLIT>
__global__ void __launch_bounds__(NTHREADS, 4)
gru_fused(const float* __restrict__ x, const float* __restrict__ h,
          const float* __restrict__ w_reset, const float* __restrict__ b_reset,
          const float* __restrict__ w_update, const float* __restrict__ b_update,
          const float* __restrict__ w_out, const float* __restrict__ b_out,
          const float* __restrict__ w_read, float* __restrict__ ws,
          float* __restrict__ out)
{
  __shared__ float sm[4][TELEMS];  // 24192 B
  const int tid  = threadIdx.x;
  const int bid  = blockIdx.x;
  const int pg   = bid & 15;
  const int tile = bid >> 4;
  const int R0 = (tile >> 3) * 32;
  const int C0 = (tile & 7) * 32;
  const int trow = tid >> 3;
  const int tcol = (tid & 7) * 4;
  const int gidx = (R0 + trow) * RCdim + C0 + tcol;

  // ring task geometry (hr halo): window base col rwb (even), rows rrow-1..rrow+1,
  // conv_acc<0> centers = rwb+1+k; write k in [rk0, rk0+rkn)
  const bool ringAct = tid < 82;
  int rrow=1, rwb=2, rk0=0, rkn=0;
  if (tid < 9)       { rrow = 1;            rwb = 2+4*tid;      rk0 = 0; rkn = (tid==8)?2:4; }
  else if (tid < 18) { int u=tid-9; rrow=34; rwb = 2+4*u;       rk0 = 0; rkn = (u==8)?2:4; }
  else if (tid < 50) { rrow = 2+(tid-18);   rwb = 2;            rk0 = 0; rkn = 1; }
  else if (tid < 82) { rrow = 2+(tid-50);   rwb = 32;           rk0 = 3; rkn = 1; }

  float acc[4] = {0.f,0.f,0.f,0.f};

#pragma unroll 1
  for (int it = 0; it < 4; ++it){
    const bool low = (it < 2);
    const int t = it & 1;
    int a, ph;
    const float *s0, *s1;
    if (low){
      a = 4*pg + 2*t; ph = 64 + 2*pg + t;
      s0 = x + (size_t)(2*a  )*IMG;
      s1 = x + (size_t)(2*a+2)*IMG;
    } else {
      a = 64 + 4*pg + 2*t; ph = 96 + 2*pg + t;
      const int base = 8*pg + 4*t;
      s0 = h + (size_t)base*IMG;
      s1 = h + (size_t)(base+2)*IMG;
    }

    __syncthreads();   // protect B0..B3 from previous iteration's readers
    stage4(s0,                     sm[0], R0,C0,tid);
    stage4(s0 + IMG,               sm[1], R0,C0,tid);
    stage4(h + (size_t)a*IMG,      sm[2], R0,C0,tid);
    __syncthreads();

    // ===== half 1: strip convs over (B0,B1), then update part1 over B2 =====
    float ra[4], uo[4], co[4];
    {
      float W0[3][8], W1[3][8];
      load8(sm[0], trow+1, tcol+2, W0);
      load8(sm[1], trow+1, tcol+2, W1);
      float wt0[9], wt1[9];
      load_w18(w_reset + a*18, wt0, wt1);
      const float br0 = b_reset[a];
      ra[0]=br0; ra[1]=br0; ra[2]=br0; ra[3]=br0;
      conv_acc<1>(W0, wt0, ra); conv_acc<1>(W1, wt1, ra);
      if (low){
        load_w18(w_update + a*18, wt0, wt1);
        const float bu = b_update[a];
        uo[0]=bu; uo[1]=bu; uo[2]=bu; uo[3]=bu;
        conv_acc<1>(W0, wt0, uo); conv_acc<1>(W1, wt1, uo);
        load_w18(w_out + a*18, wt0, wt1);
        const float bo = b_out[a];
        co[0]=bo; co[1]=bo; co[2]=bo; co[3]=bo;
        conv_acc<1>(W0, wt0, co); conv_acc<1>(W1, wt1, co);
      }
    } // W0/W1 dead

    float upd[4], hc[4];
    {
      float wh0[9];
      load_w9(w_update + ph*18, wh0);
      const float buh = b_update[ph];
      float WH[3][8];
      load8(sm[2], trow+1, tcol+2, WH);
      upd[0]=buh; upd[1]=buh; upd[2]=buh; upd[3]=buh;
      conv_acc<1>(WH, wh0, upd);
#pragma unroll
      for (int k=0;k<4;++k) hc[k] = WH[1][k+2];
    }

    if (low){
      float ns0[4];
#pragma unroll
      for (int k=0;k<4;++k){ float u=sig_(uo[k]); ns0[k]=hc[k]+u*(th_(co[k])-hc[k]); }
      if (SPLIT){
        *(float4*)&ws[(size_t)a*IMG + gidx] = make_float4(ns0[0],ns0[1],ns0[2],ns0[3]);
      } else {
#pragma unroll
        for (int k=0;k<4;++k)
          acc[k] = fmaf(ns0[k], w_read[(size_t)(gidx+k)*PCNT + a], acc[k]);
      }
    }

    float rsig[4];
    if (ringAct){
      float rv0[3][8], rv1[3][8];
      load8(sm[0], rrow-1, rwb, rv0);
      load8(sm[1], rrow-1, rwb, rv1);
      float wt0[9], wt1[9];
      load_w18(w_reset + a*18, wt0, wt1);
      const float br0 = b_reset[a];
      float rr[4] = {br0,br0,br0,br0};
      conv_acc<0>(rv0, wt0, rr); conv_acc<0>(rv1, wt1, rr);
#pragma unroll
      for (int k=0;k<4;++k) rsig[k] = sig_(rr[k]);
    }
    __syncthreads();   // all reads of B0,B1,B2 done

    // ===== half 2 stage + hr_a in-place write =====
    stage4(s1,                      sm[0], R0,C0,tid);
    stage4(s1 + IMG,                sm[1], R0,C0,tid);
    stage4(h + (size_t)(a+1)*IMG,   sm[3], R0,C0,tid);
    { // interior hr_a = h_center * sig(ra)
      float* d = &sm[2][(trow+2)*PITCH + tcol+4];
      *(float2*)(d  ) = make_float2(hc[0]*sig_(ra[0]), hc[1]*sig_(ra[1]));
      *(float2*)(d+2) = make_float2(hc[2]*sig_(ra[2]), hc[3]*sig_(ra[3]));
    }
    if (ringAct){
#pragma unroll
      for (int k=0;k<4;++k){
        if (k>=rk0 && k<rk0+rkn){
          int o = rrow*PITCH + rwb+1+k;
          sm[2][o] = sm[2][o] * rsig[k];
        }
      }
    }
    __syncthreads();

    // ===== half 2: strip convs over restaged (B0,B1), update part2 over B3 =====
    float hc2[4];
    {
      float W0[3][8], W1[3][8];
      load8(sm[0], trow+1, tcol+2, W0);
      load8(sm[1], trow+1, tcol+2, W1);
      float wt0[9], wt1[9];
      load_w18(w_reset + (a+1)*18, wt0, wt1);
      const float br1 = b_reset[a+1];
      ra[0]=br1; ra[1]=br1; ra[2]=br1; ra[3]=br1;
      conv_acc<1>(W0, wt0, ra); conv_acc<1>(W1, wt1, ra);
      if (low){
        load_w18(w_update + (a+1)*18, wt0, wt1);
        const float bu = b_update[a+1];
        uo[0]=bu; uo[1]=bu; uo[2]=bu; uo[3]=bu;
        conv_acc<1>(W0, wt0, uo); conv_acc<1>(W1, wt1, uo);
        load_w18(w_out + (a+1)*18, wt0, wt1);
        const float bo = b_out[a+1];
        co[0]=bo; co[1]=bo; co[2]=bo; co[3]=bo;
        conv_acc<1>(W0, wt0, co); conv_acc<1>(W1, wt1, co);
      }
    }
    {
      float wh1[9];
      load_w9(w_update + ph*18 + 9, wh1);
      float WH[3][8];
      load8(sm[3], trow+1, tcol+2, WH);
      conv_acc<1>(WH, wh1, upd);
#pragma unroll
      for (int k=0;k<4;++k) hc2[k] = WH[1][k+2];
    }

    if (low){
      float ns1[4];
#pragma unroll
      for (int k=0;k<4;++k){ float u=sig_(uo[k]); ns1[k]=hc2[k]+u*(th_(co[k])-hc2[k]); }
      if (SPLIT){
        *(float4*)&ws[(size_t)(a+1)*IMG + gidx] = make_float4(ns1[0],ns1[1],ns1[2],ns1[3]);
      } else {
#pragma unroll
        for (int k=0;k<4;++k)
          acc[k] = fmaf(ns1[k], w_read[(size_t)(gidx+k)*PCNT + (a+1)], acc[k]);
      }
    }

    float rsig2[4];
    if (ringAct){
      float rv0[3][8], rv1[3][8];
      load8(sm[0], rrow-1, rwb, rv0);
      load8(sm[1], rrow-1, rwb, rv1);
      float wt0[9], wt1[9];
      load_w18(w_reset + (a+1)*18, wt0, wt1);
      const float br1 = b_reset[a+1];
      float rr[4] = {br1,br1,br1,br1};
      conv_acc<0>(rv0, wt0, rr); conv_acc<0>(rv1, wt1, rr);
#pragma unroll
      for (int k=0;k<4;++k) rsig2[k] = sig_(rr[k]);
    }
    __syncthreads();   // all reads of B3 (update part2) done

    // ===== hr_{a+1} in-place write =====
    {
      float* d = &sm[3][(trow+2)*PITCH + tcol+4];
      *(float2*)(d  ) = make_float2(hc2[0]*sig_(ra[0]), hc2[1]*sig_(ra[1]));
      *(float2*)(d+2) = make_float2(hc2[2]*sig_(ra[2]), hc2[3]*sig_(ra[3]));
    }
    if (ringAct){
#pragma unroll
      for (int k=0;k<4;++k){
        if (k>=rk0 && k<rk0+rkn){
          int o = rrow*PITCH + rwb+1+k;
          sm[3][o] = sm[3][o] * rsig2[k];
        }
      }
    }
    __syncthreads();

    // ===== cand conv over (hr_a, hr_{a+1}) + blend for high plant =====
    {
      float W0[3][8], W1[3][8];
      load8(sm[2], trow+1, tcol+2, W0);
      load8(sm[3], trow+1, tcol+2, W1);
      float wt0[9], wt1[9];
      load_w18(w_out + ph*18, wt0, wt1);
      const float bo = b_out[ph];
      float cc[4]={bo,bo,bo,bo};
      conv_acc<1>(W0, wt0, cc); conv_acc<1>(W1, wt1, cc);
      const float4 hp4 = *(const float4*)&h[(size_t)ph*IMG + gidx];
      const float hp[4] = {hp4.x,hp4.y,hp4.z,hp4.w};
      float nsH[4];
#pragma unroll
      for (int k=0;k<4;++k){
        float u = sig_(upd[k]);
        nsH[k] = hp[k] + u*(th_(cc[k])-hp[k]);
      }
      if (SPLIT){
        *(float4*)&ws[(size_t)ph*IMG + gidx] = make_float4(nsH[0],nsH[1],nsH[2],nsH[3]);
      } else {
#pragma unroll
        for (int k=0;k<4;++k)
          acc[k] = fmaf(nsH[k], w_read[(size_t)(gidx+k)*PCNT + ph], acc[k]);
      }
    }
  }

  if (!SPLIT){
#pragma unroll
    for (int k=0;k<4;++k) atomicAdd(&out[gidx+k], acc[k]);
  }
}

extern "C" void kernel_launch(void* const* d_in, const int* in_sizes, int n_in,
                              void* d_out, int out_size, void* d_ws, size_t ws_size,
                              hipStream_t stream) {
  const float* x     = (const float*)d_in[0];
  const float* h     = (const float*)d_in[1];
  const float* wrst  = (const float*)d_in[2];
  const float* brst  = (const float*)d_in[3];
  const float* wupd  = (const float*)d_in[4];
  const float* bupd  = (const float*)d_in[5];
  const float* wout  = (const float*)d_in[6];
  const float* bout  = (const float*)d_in[7];
  const float* wread = (const float*)d_in[8];
  const float* bias  = (const float*)d_in[9];
  float* out = (float*)d_out;
  float* ws  = (float*)d_ws;

  const bool split = ws_size >= (size_t)PCNT * IMG * sizeof(float);
  if (split){
    hipLaunchKernelGGL(gru_fused<true>, dim3(64*16), dim3(NTHREADS), 0, stream,
                       x, h, wrst, brst, wupd, bupd, wout, bout, wread, ws, out);
    hipLaunchKernelGGL(reduce_out, dim3(IMG/NTHREADS), dim3(NTHREADS), 0, stream,
                       ws, wread, bias, out);
  } else {
    hipLaunchKernelGGL(init_out, dim3(IMG/NTHREADS), dim3(NTHREADS), 0, stream, bias, out);
    hipLaunchKernelGGL(gru_fused<false>, dim3(64*16), dim3(NTHREADS), 0, stream,
                       x, h, wrst, brst, wupd, bupd, wout, bout, wread, ws, out);
  }
}

// Round 9
// 86.935 us; speedup vs baseline: 1.9068x; 1.0861x over previous
//
#include <hip/hip_runtime.h>

#define PCNT 128
#define RCdim 256
#define IMG (RCdim*RCdim)
#define PITCH 42        // mod 4 = 2 -> rows alternate bank class (conflict fix, R5)
#define TROWS 36        // 32 + 2*ext2
#define TELEMS (TROWS*PITCH)   // 1512 floats
#define NSLOT 360              // float4 load slots per plane (10 per row)
#define NTHREADS 256
#define NTHREADS_R 128

__device__ __forceinline__ float sig_(float x){ return 1.0f/(1.0f+__expf(-x)); }
__device__ __forceinline__ float th_(float x){ float e=__expf(2.0f*x); return 1.0f-2.0f/(e+1.0f); }

// fp32 -> bf16 with round-to-nearest-even (deterministic, no API dependency)
__device__ __forceinline__ unsigned short f2bf(float f){
  unsigned u = __float_as_uint(f);
  u = (u + 0x7fffu + ((u >> 16) & 1u)) >> 16;
  return (unsigned short)u;
}
__device__ __forceinline__ float bf2f(unsigned short s){
  return __uint_as_float(((unsigned)s) << 16);
}

// Stage one 36x40 plane tile (pitch 42), origin (R0-2, C0-4), zero-padded OOB.
__device__ __forceinline__ void stage4(const float* __restrict__ src, float* __restrict__ dst,
                                       int R0, int C0, int tid){
#pragma unroll
  for (int j=0;j<2;++j){
    int s = j*NTHREADS + tid;
    if (s < NSLOT){
      int rr = s/10, q = s - rr*10;
      int gr = R0-2+rr, gc = C0-4+4*q;
      float4 v = make_float4(0.f,0.f,0.f,0.f);
      if ((unsigned)gr < 256u && (unsigned)gc < 253u)
        v = *(const float4*)(src + gr*RCdim + gc);
      float* d = dst + rr*PITCH + 4*q;
      *(float2*)(d  ) = make_float2(v.x, v.y);
      *(float2*)(d+2) = make_float2(v.z, v.w);
    }
  }
}

// 8-col window via 4x ds_read_b64 (col0 even), rows row0..row0+2
__device__ __forceinline__ void load8(const float* __restrict__ T, int row0, int col0, float v[3][8]){
#pragma unroll
  for (int dy=0;dy<3;++dy){
    const float2* p = (const float2*)&T[(row0+dy)*PITCH + col0];
    float2 a=p[0],b=p[1],c=p[2],d=p[3];
    v[dy][0]=a.x; v[dy][1]=a.y; v[dy][2]=b.x; v[dy][3]=b.y;
    v[dy][4]=c.x; v[dy][5]=c.y; v[dy][6]=d.x; v[dy][7]=d.y;
  }
}

// 3x3 cross-correlation, 1x4 strip; pixel k center col = window_base + OFF+1+k
template<int OFF>
__device__ __forceinline__ void conv_acc(const float v[3][8], const float w9[9], float o[4]){
#pragma unroll
  for (int ky=0; ky<3; ++ky)
#pragma unroll
    for (int kx=0; kx<3; ++kx){
      const float w = w9[ky*3+kx];
#pragma unroll
      for (int k=0;k<4;++k) o[k] = fmaf(w, v[ky][k+kx+OFF], o[k]);
    }
}

__device__ __forceinline__ void load_w18(const float* __restrict__ g, float w0[9], float w1[9]){
#pragma unroll
  for (int i=0;i<9;++i){ w0[i]=g[i]; w1[i]=g[9+i]; }
}

__device__ __forceinline__ void store_bf4(unsigned short* __restrict__ dst, const float v[4]){
  uint2 p;
  p.x = (unsigned)f2bf(v[0]) | ((unsigned)f2bf(v[1]) << 16);
  p.y = (unsigned)f2bf(v[2]) | ((unsigned)f2bf(v[3]) << 16);
  *(uint2*)dst = p;
}

__global__ void init_out(const float* __restrict__ bias, float* __restrict__ out){
  int i = blockIdx.x * NTHREADS + threadIdx.x;
  out[i] = bias[i];
}

// out[px] = bias[px] + sum_p ns[p][px] * w_read[px][p]; ns is bf16, 2 px per thread
__global__ void __launch_bounds__(NTHREADS_R)
reduce_out(const unsigned short* __restrict__ ns, const float* __restrict__ w_read,
           const float* __restrict__ bias, float* __restrict__ out){
  const int px0 = (blockIdx.x*NTHREADS_R + threadIdx.x)*2;
  float acc0 = bias[px0], acc1 = bias[px0+1];
  const float* wr0 = w_read + (size_t)px0*PCNT;
  const float* wr1 = wr0 + PCNT;
#pragma unroll 4
  for (int p0 = 0; p0 < PCNT; p0 += 4){
    const float4 wa = *(const float4*)&wr0[p0];
    const float4 wb = *(const float4*)&wr1[p0];
#pragma unroll
    for (int j=0;j<4;++j){
      unsigned v = *(const unsigned*)&ns[(size_t)(p0+j)*IMG + px0];
      float n0 = __uint_as_float(v << 16);
      float n1 = __uint_as_float(v & 0xffff0000u);
      const float w0 = (&wa.x)[j], w1 = (&wb.x)[j];
      acc0 = fmaf(n0, w0, acc0);
      acc1 = fmaf(n1, w1, acc1);
    }
  }
  out[px0]   = acc0;
  out[px0+1] = acc1;
}

// R5 skeleton (6 planes staged once/iter, 4 barriers/iter, launch_bounds(256,4) no-spill)
// + reset conv fused into per-thread strips (serial weight reuse) + 82-lane halo ring.
// sm0,sm1 = reset_a sources; sm2,sm3 = reset_{a+1} sources; sm4,sm5 = h_a, h_{a+1}.
// hr_a overwrites sm0 interior, hr_{a+1} overwrites sm2 (after syncC).
template<bool SPLIT>
__global__ void __launch_bounds__(NTHREADS, 4)
gru_fused(const float* __restrict__ x, const float* __restrict__ h,
          const float* __restrict__ w_reset, const float* __restrict__ b_reset,
          const float* __restrict__ w_update, const float* __restrict__ b_update,
          const float* __restrict__ w_out, const float* __restrict__ b_out,
          const float* __restrict__ w_read, unsigned short* __restrict__ wsb,
          float* __restrict__ out)
{
  __shared__ float sm[6][TELEMS];  // 36288 B
  const int tid  = threadIdx.x;
  const int bid  = blockIdx.x;
  const int pg   = bid & 15;
  const int tile = bid >> 4;
  const int R0 = (tile >> 3) * 32;
  const int C0 = (tile & 7) * 32;
  const int trow = tid >> 3;
  const int tcol = (tid & 7) * 4;
  const int gidx = (R0 + trow) * RCdim + C0 + tcol;

  // ring task geometry (hr halo): window base col rwb (even), rows rrow-1..rrow+1,
  // conv_acc<0> centers = rwb+1+k; write k in [rk0, rk0+rkn)
  const bool ringAct = tid < 82;
  int rrow=1, rwb=2, rk0=0, rkn=0;
  if (tid < 9)       { rrow = 1;            rwb = 2+4*tid;      rk0 = 0; rkn = (tid==8)?2:4; }
  else if (tid < 18) { int u=tid-9; rrow=34; rwb = 2+4*u;       rk0 = 0; rkn = (u==8)?2:4; }
  else if (tid < 50) { rrow = 2+(tid-18);   rwb = 2;            rk0 = 0; rkn = 1; }
  else if (tid < 82) { rrow = 2+(tid-50);   rwb = 32;           rk0 = 3; rkn = 1; }

  float acc[4] = {0.f,0.f,0.f,0.f};

#pragma unroll 1
  for (int it = 0; it < 4; ++it){
    const bool low = (it < 2);
    const int t = it & 1;
    int a, ph;
    const float *s0p, *s1p;
    if (low){
      a = 4*pg + 2*t; ph = 64 + 2*pg + t;
      s0p = x + (size_t)(2*a  )*IMG;   // x_{2a}, x_{2a+1}
      s1p = x + (size_t)(2*a+2)*IMG;   // x_{2a+2}, x_{2a+3}
    } else {
      a = 64 + 4*pg + 2*t; ph = 96 + 2*pg + t;
      const int base = 8*pg + 4*t;
      s0p = h + (size_t)base*IMG;
      s1p = h + (size_t)(base+2)*IMG;
    }

    __syncthreads();   // protect all planes from previous iteration's readers
    stage4(s0p,                     sm[0], R0,C0,tid);
    stage4(s0p + IMG,               sm[1], R0,C0,tid);
    stage4(s1p,                     sm[2], R0,C0,tid);
    stage4(s1p + IMG,               sm[3], R0,C0,tid);
    stage4(h + (size_t)a*IMG,       sm[4], R0,C0,tid);
    stage4(h + (size_t)(a+1)*IMG,   sm[5], R0,C0,tid);
    __syncthreads();

    // ===== update conv for ph over (h_a, h_{a+1}); capture centers =====
    float upd[4], hc[4], hc2[4];
    {
      float W0[3][8], W1[3][8];
      load8(sm[4], trow+1, tcol+2, W0);
      load8(sm[5], trow+1, tcol+2, W1);
      float wt0[9], wt1[9];
      load_w18(w_update + ph*18, wt0, wt1);
      const float bu = b_update[ph];
      upd[0]=bu; upd[1]=bu; upd[2]=bu; upd[3]=bu;
      conv_acc<1>(W0, wt0, upd); conv_acc<1>(W1, wt1, upd);
#pragma unroll
      for (int k=0;k<4;++k){ hc[k]=W0[1][k+2]; hc2[k]=W1[1][k+2]; }
    }

    // ===== strip pair a: reset (+ low-plant gates) over (sm0, sm1) =====
    float ra[4];
    {
      float W0[3][8], W1[3][8];
      load8(sm[0], trow+1, tcol+2, W0);
      load8(sm[1], trow+1, tcol+2, W1);
      float wt0[9], wt1[9];
      load_w18(w_reset + a*18, wt0, wt1);
      const float br = b_reset[a];
      ra[0]=br; ra[1]=br; ra[2]=br; ra[3]=br;
      conv_acc<1>(W0, wt0, ra); conv_acc<1>(W1, wt1, ra);
      if (low){
        load_w18(w_update + a*18, wt0, wt1);
        const float bu = b_update[a];
        float uo[4]={bu,bu,bu,bu};
        conv_acc<1>(W0, wt0, uo); conv_acc<1>(W1, wt1, uo);
        load_w18(w_out + a*18, wt0, wt1);
        const float bo = b_out[a];
        float co[4]={bo,bo,bo,bo};
        conv_acc<1>(W0, wt0, co); conv_acc<1>(W1, wt1, co);
        float ns0[4];
#pragma unroll
        for (int k=0;k<4;++k){ float u=sig_(uo[k]); ns0[k]=hc[k]+u*(th_(co[k])-hc[k]); }
        if (SPLIT){
          store_bf4(&wsb[(size_t)a*IMG + gidx], ns0);
        } else {
#pragma unroll
          for (int k=0;k<4;++k)
            acc[k] = fmaf(ns0[k], w_read[(size_t)(gidx+k)*PCNT + a], acc[k]);
        }
      }
    }

    // ===== strip pair a+1: reset (+ low-plant gates) over (sm2, sm3) =====
    float ra2[4];
    {
      float W0[3][8], W1[3][8];
      load8(sm[2], trow+1, tcol+2, W0);
      load8(sm[3], trow+1, tcol+2, W1);
      float wt0[9], wt1[9];
      load_w18(w_reset + (a+1)*18, wt0, wt1);
      const float br = b_reset[a+1];
      ra2[0]=br; ra2[1]=br; ra2[2]=br; ra2[3]=br;
      conv_acc<1>(W0, wt0, ra2); conv_acc<1>(W1, wt1, ra2);
      if (low){
        load_w18(w_update + (a+1)*18, wt0, wt1);
        const float bu = b_update[a+1];
        float uo[4]={bu,bu,bu,bu};
        conv_acc<1>(W0, wt0, uo); conv_acc<1>(W1, wt1, uo);
        load_w18(w_out + (a+1)*18, wt0, wt1);
        const float bo = b_out[a+1];
        float co[4]={bo,bo,bo,bo};
        conv_acc<1>(W0, wt0, co); conv_acc<1>(W1, wt1, co);
        float ns1[4];
#pragma unroll
        for (int k=0;k<4;++k){ float u=sig_(uo[k]); ns1[k]=hc2[k]+u*(th_(co[k])-hc2[k]); }
        if (SPLIT){
          store_bf4(&wsb[(size_t)(a+1)*IMG + gidx], ns1);
        } else {
#pragma unroll
          for (int k=0;k<4;++k)
            acc[k] = fmaf(ns1[k], w_read[(size_t)(gidx+k)*PCNT + (a+1)], acc[k]);
        }
      }
    }

    // ===== ring reset sigmoids (halo px not covered by strips) =====
    float rsig[4], rsig2[4];
    if (ringAct){
      float rv0[3][8], rv1[3][8];
      float wt0[9], wt1[9];
      load8(sm[0], rrow-1, rwb, rv0);
      load8(sm[1], rrow-1, rwb, rv1);
      load_w18(w_reset + a*18, wt0, wt1);
      const float br = b_reset[a];
      float rr[4] = {br,br,br,br};
      conv_acc<0>(rv0, wt0, rr); conv_acc<0>(rv1, wt1, rr);
#pragma unroll
      for (int k=0;k<4;++k) rsig[k] = sig_(rr[k]);
      load8(sm[2], rrow-1, rwb, rv0);
      load8(sm[3], rrow-1, rwb, rv1);
      load_w18(w_reset + (a+1)*18, wt0, wt1);
      const float br1 = b_reset[a+1];
      float rr2[4] = {br1,br1,br1,br1};
      conv_acc<0>(rv0, wt0, rr2); conv_acc<0>(rv1, wt1, rr2);
#pragma unroll
      for (int k=0;k<4;++k) rsig2[k] = sig_(rr2[k]);
    }
    __syncthreads();   // all reads of sm0..sm3 originals done

    // ===== hr writes: hr_a -> sm0, hr_{a+1} -> sm2 (interior own strip + ring) =====
    {
      float* d0 = &sm[0][(trow+2)*PITCH + tcol+4];
      *(float2*)(d0  ) = make_float2(hc[0]*sig_(ra[0]), hc[1]*sig_(ra[1]));
      *(float2*)(d0+2) = make_float2(hc[2]*sig_(ra[2]), hc[3]*sig_(ra[3]));
      float* d2 = &sm[2][(trow+2)*PITCH + tcol+4];
      *(float2*)(d2  ) = make_float2(hc2[0]*sig_(ra2[0]), hc2[1]*sig_(ra2[1]));
      *(float2*)(d2+2) = make_float2(hc2[2]*sig_(ra2[2]), hc2[3]*sig_(ra2[3]));
    }
    if (ringAct){
#pragma unroll
      for (int k=0;k<4;++k){
        if (k>=rk0 && k<rk0+rkn){
          int o = rrow*PITCH + rwb+1+k;
          sm[0][o] = sm[4][o] * rsig[k];
          sm[2][o] = sm[5][o] * rsig2[k];
        }
      }
    }
    __syncthreads();

    // ===== cand conv over (hr_a, hr_{a+1}) + blend for high plant ph =====
    {
      float W0[3][8], W1[3][8];
      load8(sm[0], trow+1, tcol+2, W0);
      load8(sm[2], trow+1, tcol+2, W1);
      float wt0[9], wt1[9];
      load_w18(w_out + ph*18, wt0, wt1);
      const float bo = b_out[ph];
      float cc[4]={bo,bo,bo,bo};
      conv_acc<1>(W0, wt0, cc); conv_acc<1>(W1, wt1, cc);
      const float4 hp4 = *(const float4*)&h[(size_t)ph*IMG + gidx];
      const float hp[4] = {hp4.x,hp4.y,hp4.z,hp4.w};
      float nsH[4];
#pragma unroll
      for (int k=0;k<4;++k){
        float u = sig_(upd[k]);
        nsH[k] = hp[k] + u*(th_(cc[k])-hp[k]);
      }
      if (SPLIT){
        store_bf4(&wsb[(size_t)ph*IMG + gidx], nsH);
      } else {
#pragma unroll
        for (int k=0;k<4;++k)
          acc[k] = fmaf(nsH[k], w_read[(size_t)(gidx+k)*PCNT + ph], acc[k]);
      }
    }
  }

  if (!SPLIT){
#pragma unroll
    for (int k=0;k<4;++k) atomicAdd(&out[gidx+k], acc[k]);
  }
}

extern "C" void kernel_launch(void* const* d_in, const int* in_sizes, int n_in,
                              void* d_out, int out_size, void* d_ws, size_t ws_size,
                              hipStream_t stream) {
  const float* x     = (const float*)d_in[0];
  const float* h     = (const float*)d_in[1];
  const float* wrst  = (const float*)d_in[2];
  const float* brst  = (const float*)d_in[3];
  const float* wupd  = (const float*)d_in[4];
  const float* bupd  = (const float*)d_in[5];
  const float* wout  = (const float*)d_in[6];
  const float* bout  = (const float*)d_in[7];
  const float* wread = (const float*)d_in[8];
  const float* bias  = (const float*)d_in[9];
  float* out = (float*)d_out;
  unsigned short* wsb = (unsigned short*)d_ws;

  const bool split = ws_size >= (size_t)PCNT * IMG * sizeof(unsigned short);
  if (split){
    hipLaunchKernelGGL(gru_fused<true>, dim3(64*16), dim3(NTHREADS), 0, stream,
                       x, h, wrst, brst, wupd, bupd, wout, bout, wread, wsb, out);
    hipLaunchKernelGGL(reduce_out, dim3(IMG/(NTHREADS_R*2)), dim3(NTHREADS_R), 0, stream,
                       wsb, wread, bias, out);
  } else {
    hipLaunchKernelGGL(init_out, dim3(IMG/NTHREADS), dim3(NTHREADS), 0, stream, bias, out);
    hipLaunchKernelGGL(gru_fused<false>, dim3(64*16), dim3(NTHREADS), 0, stream,
                       x, h, wrst, brst, wupd, bupd, wout, bout, wread, wsb, out);
  }
}

// Round 10
// 65.508 us; speedup vs baseline: 2.5304x; 1.3271x over previous
//
#include <hip/hip_runtime.h>

#define PCNT 128
#define RCdim 256
#define IMG (RCdim*RCdim)
#define PITCH 42        // mod 4 = 2 -> rows alternate bank class (conflict fix, R5)
#define TROWS 36        // 32 + 2*ext2
#define TELEMS (TROWS*PITCH)   // 1512 floats
#define NSLOT 360              // float4 load slots per plane (10 per row)
#define NTHREADS 256
#define NTHREADS_R 128
#define NTASK (34*9)           // hr strip tasks

__device__ __forceinline__ float sig_(float x){ return 1.0f/(1.0f+__expf(-x)); }
__device__ __forceinline__ float th_(float x){ float e=__expf(2.0f*x); return 1.0f-2.0f/(e+1.0f); }

// fp32 -> bf16 round-to-nearest-even
__device__ __forceinline__ unsigned short f2bf(float f){
  unsigned u = __float_as_uint(f);
  u = (u + 0x7fffu + ((u >> 16) & 1u)) >> 16;
  return (unsigned short)u;
}

__device__ __forceinline__ void store_bf4(unsigned short* __restrict__ dst, const float v[4]){
  uint2 p;
  p.x = (unsigned)f2bf(v[0]) | ((unsigned)f2bf(v[1]) << 16);
  p.y = (unsigned)f2bf(v[2]) | ((unsigned)f2bf(v[3]) << 16);
  *(uint2*)dst = p;
}

// Stage one 36x40 plane tile (pitch 42), origin (R0-2, C0-4), zero-padded OOB.
__device__ __forceinline__ void stage4(const float* __restrict__ src, float* __restrict__ dst,
                                       int R0, int C0, int tid){
#pragma unroll
  for (int j=0;j<2;++j){
    int s = j*NTHREADS + tid;
    if (s < NSLOT){
      int rr = s/10, q = s - rr*10;
      int gr = R0-2+rr, gc = C0-4+4*q;
      float4 v = make_float4(0.f,0.f,0.f,0.f);
      if ((unsigned)gr < 256u && (unsigned)gc < 253u)
        v = *(const float4*)(src + gr*RCdim + gc);
      float* d = dst + rr*PITCH + 4*q;
      *(float2*)(d  ) = make_float2(v.x, v.y);
      *(float2*)(d+2) = make_float2(v.z, v.w);
    }
  }
}

// 8-col window via 4x ds_read_b64 (col0 even), rows row0..row0+2
__device__ __forceinline__ void load8(const float* __restrict__ T, int row0, int col0, float v[3][8]){
#pragma unroll
  for (int dy=0;dy<3;++dy){
    const float2* p = (const float2*)&T[(row0+dy)*PITCH + col0];
    float2 a=p[0],b=p[1],c=p[2],d=p[3];
    v[dy][0]=a.x; v[dy][1]=a.y; v[dy][2]=b.x; v[dy][3]=b.y;
    v[dy][4]=c.x; v[dy][5]=c.y; v[dy][6]=d.x; v[dy][7]=d.y;
  }
}

// 3x3 cross-correlation, 1x4 strip; pixel k center col = window_base + OFF+1+k
template<int OFF>
__device__ __forceinline__ void conv_acc(const float v[3][8], const float w9[9], float o[4]){
#pragma unroll
  for (int ky=0; ky<3; ++ky)
#pragma unroll
    for (int kx=0; kx<3; ++kx){
      const float w = w9[ky*3+kx];
#pragma unroll
      for (int k=0;k<4;++k) o[k] = fmaf(w, v[ky][k+kx+OFF], o[k]);
    }
}

__device__ __forceinline__ void load_w18(const float* __restrict__ g, float w0[9], float w1[9]){
#pragma unroll
  for (int i=0;i<9;++i){ w0[i]=g[i]; w1[i]=g[9+i]; }
}

// Reset-gate sigmoids for pair (a, a+1) into registers (R5 spill-free pattern).
__device__ __forceinline__ void hr_compute(float (*sm)[TELEMS],
    const float* __restrict__ w_reset, const float* __restrict__ b_reset,
    int a, int tid, float ga[2][4], float gb[2][4]){
  float wr0[9],wr1[9],ws0[9],ws1[9];
  load_w18(w_reset + a*18,     wr0, wr1);
  load_w18(w_reset + (a+1)*18, ws0, ws1);
  const float bra = b_reset[a], brb = b_reset[a+1];
#pragma unroll
  for (int j=0;j<2;++j){
    int sIdx = j*NTHREADS + tid;
    if (sIdx < NTASK){
      int row = sIdx/9, s = sIdx - row*9;
      int rr = row + 1, col0 = 4*s;
      float va[3][8], vb[3][8];
      load8(sm[0], rr-1, col0, va);
      load8(sm[1], rr-1, col0, vb);
      float ra[4] = {bra,bra,bra,bra};
      conv_acc<2>(va, wr0, ra); conv_acc<2>(vb, wr1, ra);
      load8(sm[2], rr-1, col0, va);
      load8(sm[3], rr-1, col0, vb);
      float rb[4] = {brb,brb,brb,brb};
      conv_acc<2>(va, ws0, rb); conv_acc<2>(vb, ws1, rb);
#pragma unroll
      for (int k=0;k<4;++k){ ga[j][k]=sig_(ra[k]); gb[j][k]=sig_(rb[k]); }
    }
  }
}

// hr_a -> sm[0] interior, hr_{a+1} -> sm[2] interior (rows 1..34, cols 3..36).
__device__ __forceinline__ void hr_write(float (*sm)[TELEMS], int tid,
    const float ga[2][4], const float gb[2][4]){
#pragma unroll
  for (int j=0;j<2;++j){
    int sIdx = j*NTHREADS + tid;
    if (sIdx < NTASK){
      int row = sIdx/9, s = sIdx - row*9;
      int rr = row + 1, col0 = 4*s;
      int cnt = (s==8) ? 2 : 4;
      for (int k=0;k<cnt;++k){
        int o = rr*PITCH + col0 + 3 + k;
        sm[0][o] = sm[4][o] * ga[j][k];
        sm[2][o] = sm[5][o] * gb[j][k];
      }
    }
  }
}

__global__ void init_out(const float* __restrict__ bias, float* __restrict__ out){
  int i = blockIdx.x * NTHREADS + threadIdx.x;
  out[i] = bias[i];
}

// out[px] = bias[px] + sum_p ns[p][px] * w_read[px][p]; ns is bf16, 2 px per thread
__global__ void __launch_bounds__(NTHREADS_R)
reduce_out(const unsigned short* __restrict__ ns, const float* __restrict__ w_read,
           const float* __restrict__ bias, float* __restrict__ out){
  const int px0 = (blockIdx.x*NTHREADS_R + threadIdx.x)*2;
  float acc0 = bias[px0], acc1 = bias[px0+1];
  const float* wr0 = w_read + (size_t)px0*PCNT;
  const float* wr1 = wr0 + PCNT;
#pragma unroll 4
  for (int p0 = 0; p0 < PCNT; p0 += 4){
    const float4 wa = *(const float4*)&wr0[p0];
    const float4 wb = *(const float4*)&wr1[p0];
#pragma unroll
    for (int j=0;j<4;++j){
      unsigned v = *(const unsigned*)&ns[(size_t)(p0+j)*IMG + px0];
      float n0 = __uint_as_float(v << 16);
      float n1 = __uint_as_float(v & 0xffff0000u);
      acc0 = fmaf(n0, (&wa.x)[j], acc0);
      acc1 = fmaf(n1, (&wb.x)[j], acc1);
    }
  }
  out[px0]   = acc0;
  out[px0+1] = acc1;
}

// R5 structure exactly (spill-free at launch_bounds(256,4)); SPLIT stores bf16 ns.
template<bool SPLIT>
__global__ void __launch_bounds__(NTHREADS, 4)
gru_fused(const float* __restrict__ x, const float* __restrict__ h,
          const float* __restrict__ w_reset, const float* __restrict__ b_reset,
          const float* __restrict__ w_update, const float* __restrict__ b_update,
          const float* __restrict__ w_out, const float* __restrict__ b_out,
          const float* __restrict__ w_read, unsigned short* __restrict__ wsb,
          float* __restrict__ out)
{
  __shared__ float sm[6][TELEMS];  // 36288 B -> 4 blocks/CU
  const int tid  = threadIdx.x;
  const int bid  = blockIdx.x;
  const int pg   = bid & 15;
  const int tile = bid >> 4;
  const int R0 = (tile >> 3) * 32;
  const int C0 = (tile & 7) * 32;
  const int trow = tid >> 3;
  const int tcol = (tid & 7) * 4;
  const int gidx = (R0 + trow) * RCdim + C0 + tcol;

  float acc[4] = {0.f,0.f,0.f,0.f};
  float v0[3][8], v1[3][8];

  // ==== Phase A: a = 4pg+2t -> low a, low a+1, high 64+2pg+t ====
#pragma unroll 1
  for (int t = 0; t < 2; ++t){
    const int a  = 4*pg + 2*t;
    const int ph = 64 + 2*pg + t;
    __syncthreads();
    stage4(x + (size_t)(2*a  )*IMG, sm[0], R0,C0,tid);
    stage4(x + (size_t)(2*a+1)*IMG, sm[1], R0,C0,tid);
    stage4(x + (size_t)(2*a+2)*IMG, sm[2], R0,C0,tid);
    stage4(x + (size_t)(2*a+3)*IMG, sm[3], R0,C0,tid);
    stage4(h + (size_t)(a    )*IMG, sm[4], R0,C0,tid);
    stage4(h + (size_t)(a+1  )*IMG, sm[5], R0,C0,tid);
    __syncthreads();

    float hc0[4], hc1[4], uH[4];
    { // high update conv (h_a, h_{a+1}); capture h centers for lows
      float wa[9], wb[9];
      load_w18(w_update + ph*18, wa, wb);
      const float b = b_update[ph];
      float uo[4] = {b,b,b,b};
      load8(sm[4], trow+1, tcol+2, v0);
      load8(sm[5], trow+1, tcol+2, v1);
      conv_acc<1>(v0, wa, uo); conv_acc<1>(v1, wb, uo);
#pragma unroll
      for (int k=0;k<4;++k){ hc0[k]=v0[1][k+2]; hc1[k]=v1[1][k+2]; uH[k]=sig_(uo[k]); }
    }
    { // low plant a
      float wua[9],wub[9],woa[9],wob[9];
      load_w18(w_update + a*18, wua, wub);
      load_w18(w_out    + a*18, woa, wob);
      const float bu=b_update[a], bo=b_out[a];
      float uo[4]={bu,bu,bu,bu}, co[4]={bo,bo,bo,bo};
      load8(sm[0], trow+1, tcol+2, v0);
      load8(sm[1], trow+1, tcol+2, v1);
      conv_acc<1>(v0, wua, uo); conv_acc<1>(v1, wub, uo);
      conv_acc<1>(v0, woa, co); conv_acc<1>(v1, wob, co);
      float ns0[4];
#pragma unroll
      for (int k=0;k<4;++k){ float u=sig_(uo[k]); ns0[k]=hc0[k]+u*(th_(co[k])-hc0[k]); }
      if (SPLIT){
        store_bf4(&wsb[(size_t)a*IMG + gidx], ns0);
      } else {
#pragma unroll
        for (int k=0;k<4;++k)
          acc[k] = fmaf(ns0[k], w_read[(size_t)(gidx+k)*PCNT + a], acc[k]);
      }
    }
    { // low plant a+1
      float wua[9],wub[9],woa[9],wob[9];
      load_w18(w_update + (a+1)*18, wua, wub);
      load_w18(w_out    + (a+1)*18, woa, wob);
      const float bu=b_update[a+1], bo=b_out[a+1];
      float uo[4]={bu,bu,bu,bu}, co[4]={bo,bo,bo,bo};
      load8(sm[2], trow+1, tcol+2, v0);
      load8(sm[3], trow+1, tcol+2, v1);
      conv_acc<1>(v0, wua, uo); conv_acc<1>(v1, wub, uo);
      conv_acc<1>(v0, woa, co); conv_acc<1>(v1, wob, co);
      float ns1[4];
#pragma unroll
      for (int k=0;k<4;++k){ float u=sig_(uo[k]); ns1[k]=hc1[k]+u*(th_(co[k])-hc1[k]); }
      if (SPLIT){
        store_bf4(&wsb[(size_t)(a+1)*IMG + gidx], ns1);
      } else {
#pragma unroll
        for (int k=0;k<4;++k)
          acc[k] = fmaf(ns1[k], w_read[(size_t)(gidx+k)*PCNT + (a+1)], acc[k]);
      }
    }
    float ga[2][4], gb[2][4];
    hr_compute(sm, w_reset, b_reset, a, tid, ga, gb);
    __syncthreads();
    hr_write(sm, tid, ga, gb);
    __syncthreads();
    { // high cand conv (hr pair) + blend
      float woa[9], wob[9];
      load_w18(w_out + ph*18, woa, wob);
      const float bo = b_out[ph];
      float co[4]={bo,bo,bo,bo};
      load8(sm[0], trow+1, tcol+2, v0);
      load8(sm[2], trow+1, tcol+2, v1);
      conv_acc<1>(v0, woa, co); conv_acc<1>(v1, wob, co);
      const float4 hp4 = *(const float4*)&h[(size_t)ph*IMG + gidx];
      const float hp[4] = {hp4.x,hp4.y,hp4.z,hp4.w};
      float nsH[4];
#pragma unroll
      for (int k=0;k<4;++k) nsH[k] = hp[k] + uH[k]*(th_(co[k])-hp[k]);
      if (SPLIT){
        store_bf4(&wsb[(size_t)ph*IMG + gidx], nsH);
      } else {
#pragma unroll
        for (int k=0;k<4;++k)
          acc[k] = fmaf(nsH[k], w_read[(size_t)(gidx+k)*PCNT + ph], acc[k]);
      }
    }
  }

  // ==== Phase B: a = 64+4pg+2t -> high plant 96+2pg+t ====
#pragma unroll 1
  for (int t = 0; t < 2; ++t){
    const int a    = 64 + 4*pg + 2*t;
    const int ph   = 96 + 2*pg + t;
    const int base = 8*pg + 4*t;
    __syncthreads();
    stage4(h + (size_t)(base  )*IMG, sm[0], R0,C0,tid);
    stage4(h + (size_t)(base+1)*IMG, sm[1], R0,C0,tid);
    stage4(h + (size_t)(base+2)*IMG, sm[2], R0,C0,tid);
    stage4(h + (size_t)(base+3)*IMG, sm[3], R0,C0,tid);
    stage4(h + (size_t)(a     )*IMG, sm[4], R0,C0,tid);
    stage4(h + (size_t)(a+1   )*IMG, sm[5], R0,C0,tid);
    __syncthreads();

    float uH[4];
    {
      float wa[9], wb[9];
      load_w18(w_update + ph*18, wa, wb);
      const float bu = b_update[ph];
      float uo[4] = {bu,bu,bu,bu};
      load8(sm[4], trow+1, tcol+2, v0);
      load8(sm[5], trow+1, tcol+2, v1);
      conv_acc<1>(v0, wa, uo); conv_acc<1>(v1, wb, uo);
#pragma unroll
      for (int k=0;k<4;++k) uH[k]=sig_(uo[k]);
    }
    float ga[2][4], gb[2][4];
    hr_compute(sm, w_reset, b_reset, a, tid, ga, gb);
    __syncthreads();
    hr_write(sm, tid, ga, gb);
    __syncthreads();
    {
      float wa[9], wb[9];
      load_w18(w_out + ph*18, wa, wb);
      const float bo = b_out[ph];
      float co[4] = {bo,bo,bo,bo};
      load8(sm[0], trow+1, tcol+2, v0);
      load8(sm[2], trow+1, tcol+2, v1);
      conv_acc<1>(v0, wa, co); conv_acc<1>(v1, wb, co);
      const float4 hp4 = *(const float4*)&h[(size_t)ph*IMG + gidx];
      const float hp[4] = {hp4.x,hp4.y,hp4.z,hp4.w};
      float nsH[4];
#pragma unroll
      for (int k=0;k<4;++k) nsH[k] = hp[k] + uH[k]*(th_(co[k])-hp[k]);
      if (SPLIT){
        store_bf4(&wsb[(size_t)ph*IMG + gidx], nsH);
      } else {
#pragma unroll
        for (int k=0;k<4;++k)
          acc[k] = fmaf(nsH[k], w_read[(size_t)(gidx+k)*PCNT + ph], acc[k]);
      }
    }
  }

  if (!SPLIT){
#pragma unroll
    for (int k=0;k<4;++k) atomicAdd(&out[gidx+k], acc[k]);
  }
}

extern "C" void kernel_launch(void* const* d_in, const int* in_sizes, int n_in,
                              void* d_out, int out_size, void* d_ws, size_t ws_size,
                              hipStream_t stream) {
  const float* x     = (const float*)d_in[0];
  const float* h     = (const float*)d_in[1];
  const float* wrst  = (const float*)d_in[2];
  const float* brst  = (const float*)d_in[3];
  const float* wupd  = (const float*)d_in[4];
  const float* bupd  = (const float*)d_in[5];
  const float* wout  = (const float*)d_in[6];
  const float* bout  = (const float*)d_in[7];
  const float* wread = (const float*)d_in[8];
  const float* bias  = (const float*)d_in[9];
  float* out = (float*)d_out;
  unsigned short* wsb = (unsigned short*)d_ws;

  const bool split = ws_size >= (size_t)PCNT * IMG * sizeof(unsigned short);
  if (split){
    hipLaunchKernelGGL(gru_fused<true>, dim3(64*16), dim3(NTHREADS), 0, stream,
                       x, h, wrst, brst, wupd, bupd, wout, bout, wread, wsb, out);
    hipLaunchKernelGGL(reduce_out, dim3(IMG/(NTHREADS_R*2)), dim3(NTHREADS_R), 0, stream,
                       wsb, wread, bias, out);
  } else {
    hipLaunchKernelGGL(init_out, dim3(IMG/NTHREADS), dim3(NTHREADS), 0, stream, bias, out);
    hipLaunchKernelGGL(gru_fused<false>, dim3(64*16), dim3(NTHREADS), 0, stream,
                       x, h, wrst, brst, wupd, bupd, wout, bout, wread, wsb, out);
  }
}